// Round 10
// baseline (75.658 us; speedup 1.0000x reference)
//
#include <hip/hip_runtime.h>

// ---------------------------------------------------------------------------
// y = x @ Q^T where Q = H_0 H_1 ... H_{N-1}, H_n = I - 2 v_n v_n^T/(v_n.v_n+eps)
// S=256, N=258, B=65536.
// Phase 1: u_n = sqrt(2/(v_n.v_n+eps)) * v_n  (rows 258..271 zeroed: no-op pad)
// Phase 2: 8 parallel chunk cascades Q_c = H_{33c}..H_{33c+32} (33-step chains)
// Phase 2b: merge tree P=Qc*Qc, R=P*P, Q=R*R via bf16 hi/lo split MFMA
//           (3-term tf32x3-style, ~1e-4 rel err, no LDS -- R8's hh_mm was
//           LDS-pipe-bound at ~10us/level; this is ~1-2us/level).
// Phase 3: GEMM y[b][j] = sum_k x[b][k] Qb[j][k]  (BT layout, bf16 MFMA)
//
// Scratch: d_ws holds u (272KB) + Qb (128KB). Qc/P/R (3.5MB) live in d_out
// (64MB), written before read every call, fully overwritten by hh_gemm.
// ---------------------------------------------------------------------------

#define GLOAD_LDS16(g, l)                                                      \
  __builtin_amdgcn_global_load_lds(                                            \
      (const __attribute__((address_space(1))) void*)(g),                      \
      (__attribute__((address_space(3))) void*)(l), 16, 0, 0)

typedef __attribute__((ext_vector_type(8))) short bf16x8;
typedef __attribute__((ext_vector_type(4))) float f32x4;

__device__ __forceinline__ unsigned short f2bf_rne(float f) {
  unsigned u = __builtin_bit_cast(unsigned, f);
  return (unsigned short)((u + 0x7fffu + ((u >> 16) & 1u)) >> 16);
}

struct bfpair { short hi, lo; };

// split fp32 -> hi(bf16) + lo(bf16), x ~= hi + lo, |err| ~ 2^-16 |x|
__device__ __forceinline__ bfpair bf_split(float x) {
  unsigned short hu = f2bf_rne(x);
  float hf = __builtin_bit_cast(float, (unsigned)hu << 16);
  bfpair r;
  r.hi = (short)hu;
  r.lo = (short)f2bf_rne(x - hf);
  return r;
}

// DPP-shuffled add: v + dpp(v). CTRL: 0xB1=quad xor1, 0x4E=quad xor2,
// 0x124=row_ror:4, 0x128=row_ror:8. Pure VALU latency, no LDS.
template <int CTRL>
__device__ __forceinline__ float dpp_add(float v) {
  int t = __builtin_amdgcn_update_dpp(0, __builtin_bit_cast(int, v), CTRL, 0xF,
                                      0xF, true);
  return v + __builtin_bit_cast(float, t);
}

// ---------------- Phase 1: scaled vectors u --------------------------------
__global__ void hh_scale(const float* __restrict__ vecs, float* __restrict__ u) {
  const int n = blockIdx.x;   // 0..271
  const int l = threadIdx.x;  // 0..63
  float4* uo = (float4*)(u + (long)n * 256) + l;
  if (n >= 258) {
    *uo = make_float4(0.f, 0.f, 0.f, 0.f);
    return;
  }
  const float4 v = *((const float4*)(vecs + (long)n * 256) + l);
  float p = v.x * v.x + v.y * v.y + v.z * v.z + v.w * v.w;
#pragma unroll
  for (int off = 32; off; off >>= 1) p += __shfl_xor(p, off);
  const float s = sqrtf(2.0f / (p + 1e-16f));
  *uo = make_float4(v.x * s, v.y * s, v.z * s, v.w * s);
}

// ---------------- Phase 2: chunked Q rows (plain C++) ----------------------
// 512 blocks x 64 threads. Block = (chunk c = bx>>6, rowgroup bx&63).
// Each block computes 4 rows of Q_c = H_{33c}..H_{33c+32} (33 steps);
// per-step dot-reduce stays in a 16-lane DPP row.
__launch_bounds__(64, 1)
__global__ void hh_qchunk(const float* __restrict__ u,
                          float* __restrict__ Qc) {
  const int l = threadIdx.x;
  const int chunk = blockIdx.x >> 6;   // 0..7
  const int rg = blockIdx.x & 63;      // 0..63
  const int r = l >> 4;
  const int c = l & 15;
  const int row = rg * 4 + r;
  const int col0 = c * 16;

  float q[16];
#pragma unroll
  for (int i = 0; i < 16; ++i) q[i] = (col0 + i == row) ? 1.f : 0.f;

  const float* ub = u + (long)chunk * 33 * 256 + col0;

  auto load16 = [&](float(&d)[16], int n) {
    const float4* v = (const float4*)(ub + (long)n * 256);
#pragma unroll
    for (int i = 0; i < 4; ++i) {
      float4 t = v[i];
      d[4 * i] = t.x; d[4 * i + 1] = t.y; d[4 * i + 2] = t.z; d[4 * i + 3] = t.w;
    }
  };

  auto step = [&](const float(&a)[16]) {
    float p0 = 0.f, p1 = 0.f, p2 = 0.f, p3 = 0.f;
#pragma unroll
    for (int e = 0; e < 4; ++e) {
      p0 = fmaf(q[e], a[e], p0);
      p1 = fmaf(q[4 + e], a[4 + e], p1);
      p2 = fmaf(q[8 + e], a[8 + e], p2);
      p3 = fmaf(q[12 + e], a[12 + e], p3);
    }
    float p = (p0 + p1) + (p2 + p3);
    p = dpp_add<0xB1>(p);
    p = dpp_add<0x4E>(p);
    p = dpp_add<0x124>(p);
    p = dpp_add<0x128>(p);
#pragma unroll
    for (int k = 0; k < 16; ++k) q[k] = fmaf(-p, a[k], q[k]);
  };

  float A0[16], A1[16];
  load16(A0, 0);
  load16(A1, 1);
  for (int n = 0; n < 32; n += 2) {
    step(A0);
    load16(A0, n + 2);
    step(A1);
    load16(A1, n + 3);  // row 33c+33 <= 264 < 272 pad, harmless
  }
  step(A0);  // step 32

  float4* out = (float4*)(Qc + (long)chunk * 65536 + row * 256 + col0);
#pragma unroll
  for (int i = 0; i < 4; ++i)
    out[i] = make_float4(q[4 * i], q[4 * i + 1], q[4 * i + 2], q[4 * i + 3]);
}

// ---------------- Phase 2b: split-MFMA merge -------------------------------
// C_b = A_b * B_b for consecutive fp32 256x256 pairs in `in`.
// bf16 hi/lo split, 3-term MFMA (hi*hi + hi*lo + lo*hi), fp32 accumulate.
// No LDS: fragments load directly from global (matrices are L2-resident).
// Grid: batch*16 blocks x 256 thr. Block tile 64x64 (2x2 waves of 32x32).
// to_bf16: last level writes bf16 Qb.
__launch_bounds__(256)
__global__ void hh_merge(const float* __restrict__ in, float* __restrict__ out,
                         unsigned short* __restrict__ outb, int to_bf16) {
  const int b = blockIdx.x >> 4;
  const int t = blockIdx.x & 15;
  const int bi = (t >> 2) * 64, bj = (t & 3) * 64;
  const int tid = threadIdx.x;
  const int lane = tid & 63, wid = tid >> 6;
  const int wm = wid >> 1, wn = wid & 1;
  const int fr = lane & 15, fg = lane >> 4;
  const float* A = in + (long)b * 2 * 65536;
  const float* Bm = A + 65536;

  const int ar0 = bi + wm * 32;  // wave's A row base
  const int bc0 = bj + wn * 32;  // wave's B col base

  f32x4 acc[2][2];
#pragma unroll
  for (int m = 0; m < 2; ++m)
#pragma unroll
    for (int n = 0; n < 2; ++n) acc[m][n] = (f32x4){0.f, 0.f, 0.f, 0.f};

  for (int kt = 0; kt < 8; ++kt) {
    const int k0 = kt * 32 + fg * 8;
    bf16x8 ahi[2], alo[2], bhi[2], blo[2];
    // A-frag: lane(fr,fg) holds A[ar0+m*16+fr][k0 .. k0+7]
#pragma unroll
    for (int m = 0; m < 2; ++m) {
      const float* ap = A + (long)(ar0 + m * 16 + fr) * 256 + k0;
      f32x4 x0 = *(const f32x4*)ap;
      f32x4 x1 = *(const f32x4*)(ap + 4);
#pragma unroll
      for (int e = 0; e < 4; ++e) {
        bfpair p0 = bf_split(x0[e]);
        bfpair p1 = bf_split(x1[e]);
        ahi[m][e] = p0.hi; alo[m][e] = p0.lo;
        ahi[m][4 + e] = p1.hi; alo[m][4 + e] = p1.lo;
      }
    }
    // B-frag: lane(fr,fg) holds B[k0+e][bc0+n*16+fr] (column walk, stride 256)
#pragma unroll
    for (int n = 0; n < 2; ++n) {
      const float* bp = Bm + (long)k0 * 256 + bc0 + n * 16 + fr;
#pragma unroll
      for (int e = 0; e < 8; ++e) {
        bfpair pb = bf_split(bp[e * 256]);
        bhi[n][e] = pb.hi; blo[n][e] = pb.lo;
      }
    }
#pragma unroll
    for (int m = 0; m < 2; ++m)
#pragma unroll
      for (int n = 0; n < 2; ++n) {
        acc[m][n] = __builtin_amdgcn_mfma_f32_16x16x32_bf16(ahi[m], bhi[n],
                                                            acc[m][n], 0, 0, 0);
        acc[m][n] = __builtin_amdgcn_mfma_f32_16x16x32_bf16(ahi[m], blo[n],
                                                            acc[m][n], 0, 0, 0);
        acc[m][n] = __builtin_amdgcn_mfma_f32_16x16x32_bf16(alo[m], bhi[n],
                                                            acc[m][n], 0, 0, 0);
      }
  }

  // C/D layout: col = lane&15, row = (lane>>4)*4 + reg
#pragma unroll
  for (int m = 0; m < 2; ++m)
#pragma unroll
    for (int n = 0; n < 2; ++n)
#pragma unroll
      for (int rr = 0; rr < 4; ++rr) {
        const int grow = ar0 + m * 16 + fg * 4 + rr;
        const int gcol = bc0 + n * 16 + fr;
        if (to_bf16)
          outb[(long)b * 65536 + grow * 256 + gcol] = f2bf_rne(acc[m][n][rr]);
        else
          out[(long)b * 65536 + grow * 256 + gcol] = acc[m][n][rr];
      }
}

// ---------------- Phase 3: GEMM --------------------------------------------
// C[M=65536][256] = A[M][K=256](f32, cvt->bf16) * B[N=256][K=256](bf16, BT)
// Block: BM=128, BN=256, BK=32, 512 thr (8 waves). Wave grid 2x4, 64x64/wave.
// LDS 64KB dbuf; XOR-swizzled staging via pre-swizzled GLOBAL source address.
__launch_bounds__(512)
__global__ void hh_gemm(const float* __restrict__ X,
                        const unsigned short* __restrict__ Qb,
                        float* __restrict__ Y) {
  __shared__ __align__(128) char lds[65536];
  const int tid = threadIdx.x;
  const int lane = tid & 63;
  const int wid = tid >> 6;
  const int wm = wid >> 2;  // 0..1
  const int wn = wid & 3;   // 0..3
  const int fr = lane & 15;
  const int fg = lane >> 4;
  const long bm0 = (long)blockIdx.x * 128;

  auto stage = [&](int buf, int kt) {
#pragma unroll
    for (int r2 = 0; r2 < 2; ++r2) {
      int slot = r2 * 512 + tid;
      int row = slot >> 3, seg = slot & 7;
      int ps = seg ^ (row & 7);
      GLOAD_LDS16(X + (bm0 + row) * 256 + kt * 32 + ps * 4,
                  lds + buf * 16384 + slot * 16);
    }
#pragma unroll
    for (int r2 = 0; r2 < 2; ++r2) {
      int slot = r2 * 512 + tid;
      int row = slot >> 2, seg = slot & 3;
      int ps = seg ^ (row & 3);
      GLOAD_LDS16(Qb + row * 256 + kt * 32 + ps * 8,
                  lds + 32768 + buf * 16384 + slot * 16);
    }
  };

  f32x4 acc[4][4];
#pragma unroll
  for (int m = 0; m < 4; ++m)
#pragma unroll
    for (int n = 0; n < 4; ++n) acc[m][n] = (f32x4){0.f, 0.f, 0.f, 0.f};

  stage(0, 0);
  __syncthreads();

  for (int kt = 0; kt < 8; ++kt) {
    const int cur = kt & 1;
    if (kt < 7) stage(cur ^ 1, kt + 1);

    bf16x8 aF[4], bF[4];
#pragma unroll
    for (int m = 0; m < 4; ++m) {
      int row = wm * 64 + m * 16 + fr;
      int s0 = (2 * fg) ^ (row & 7);
      int s1 = (2 * fg + 1) ^ (row & 7);
      const f32x4 x0 = *(const f32x4*)(lds + cur * 16384 + row * 128 + s0 * 16);
      const f32x4 x1 = *(const f32x4*)(lds + cur * 16384 + row * 128 + s1 * 16);
      bf16x8 t;
      t[0] = (short)f2bf_rne(x0[0]);
      t[1] = (short)f2bf_rne(x0[1]);
      t[2] = (short)f2bf_rne(x0[2]);
      t[3] = (short)f2bf_rne(x0[3]);
      t[4] = (short)f2bf_rne(x1[0]);
      t[5] = (short)f2bf_rne(x1[1]);
      t[6] = (short)f2bf_rne(x1[2]);
      t[7] = (short)f2bf_rne(x1[3]);
      aF[m] = t;
    }
#pragma unroll
    for (int n = 0; n < 4; ++n) {
      int row = wn * 64 + n * 16 + fr;
      int ps = fg ^ (row & 3);
      bF[n] = *(const bf16x8*)(lds + 32768 + cur * 16384 + row * 64 + ps * 16);
    }
#pragma unroll
    for (int m = 0; m < 4; ++m)
#pragma unroll
      for (int n = 0; n < 4; ++n)
        acc[m][n] =
            __builtin_amdgcn_mfma_f32_16x16x32_bf16(aF[m], bF[n], acc[m][n], 0, 0, 0);
    __syncthreads();
  }

#pragma unroll
  for (int m = 0; m < 4; ++m)
#pragma unroll
    for (int n = 0; n < 4; ++n)
#pragma unroll
      for (int r = 0; r < 4; ++r) {
        long grow = bm0 + wm * 64 + m * 16 + fg * 4 + r;
        int gcol = wn * 64 + n * 16 + fr;
        Y[grow * 256 + gcol] = acc[m][n][r];
      }
}

// ---------------------------------------------------------------------------
extern "C" void kernel_launch(void* const* d_in, const int* in_sizes, int n_in,
                              void* d_out, int out_size, void* d_ws, size_t ws_size,
                              hipStream_t stream) {
  const float* x = (const float*)d_in[0];      // [65536][256] f32
  const float* vecs = (const float*)d_in[1];   // [258][256] f32
  float* y = (float*)d_out;                    // [65536][256] f32

  // d_ws: small buffers only (R5-proven footprint)
  char* ws = (char*)d_ws;
  float* u = (float*)ws;                                // 272x256 f32 (278528 B)
  unsigned short* Qb = (unsigned short*)(ws + 278528);  // 256x256 bf16 (131072 B)

  // Large intermediates in d_out scratch (dead before hh_gemm overwrites all)
  char* ob = (char*)d_out;
  float* Qc = (float*)(ob);                 // 8 x 256x256 f32 (2 MB)
  float* P = (float*)(ob + 2097152);        // 4 x 256x256 f32 (1 MB)
  float* R = (float*)(ob + 3145728);        // 2 x 256x256 f32 (512 KB)

  hh_scale<<<272, 64, 0, stream>>>(vecs, u);
  hh_qchunk<<<512, 64, 0, stream>>>(u, Qc);
  hh_merge<<<64, 256, 0, stream>>>(Qc, P, nullptr, 0);   // 4 pair-products
  hh_merge<<<32, 256, 0, stream>>>(P, R, nullptr, 0);    // 2 pair-products
  hh_merge<<<16, 256, 0, stream>>>(R, nullptr, Qb, 1);   // final -> bf16 Qb
  hh_gemm<<<512, 512, 0, stream>>>(x, Qb, y);
}

// Round 11
// 71.224 us; speedup vs baseline: 1.0623x; 1.0623x over previous
//
#include <hip/hip_runtime.h>

// ---------------------------------------------------------------------------
// y = x @ Q^T where Q = H_0 H_1 ... H_{N-1}, H_n = I - 2 v_n v_n^T/(v_n.v_n+eps)
// S=256, N=258, B=65536.
// Phase 1: u_n = sqrt(2/(v_n.v_n+eps)) * v_n  (rows 258..271 zeroed: no-op pad)
// Phase 2: 8 parallel chunk cascades Q_c = H_{33c}..H_{33c+32}; writes Qc AND
//          Qc^T (transposed copy costs only scatter STORES, which don't stall;
//          it buys fully VECTOR loads in the merge tree).
// Phase 2b: merge tree P=Qc*Qc, R=P*P, Q=R*R via bf16 hi/lo split MFMA.
//          All operand loads are f32x4 along k (A row-major, B via B^T).
//          R10's 13us/level was latency-bound scalar column loads + tiny
//          grids; this round: vector loads + 64-thr blocks (4x more blocks).
// Phase 3: GEMM y[b][j] = sum_k x[b][k] Qb[j][k]  (BT layout, bf16 MFMA)
//
// Scratch: d_ws holds u (272KB) + Qb (128KB). Qc/QcT/P/PT/R/RT (7MB) live in
// d_out (64MB), written before read every call, overwritten by hh_gemm.
// ---------------------------------------------------------------------------

#define GLOAD_LDS16(g, l)                                                      \
  __builtin_amdgcn_global_load_lds(                                            \
      (const __attribute__((address_space(1))) void*)(g),                      \
      (__attribute__((address_space(3))) void*)(l), 16, 0, 0)

typedef __attribute__((ext_vector_type(8))) short bf16x8;
typedef __attribute__((ext_vector_type(4))) float f32x4;

__device__ __forceinline__ unsigned short f2bf_rne(float f) {
  unsigned u = __builtin_bit_cast(unsigned, f);
  return (unsigned short)((u + 0x7fffu + ((u >> 16) & 1u)) >> 16);
}

struct bfpair { short hi, lo; };

// split fp32 -> hi(bf16) + lo(bf16), x ~= hi + lo, |err| ~ 2^-16 |x|
__device__ __forceinline__ bfpair bf_split(float x) {
  unsigned short hu = f2bf_rne(x);
  float hf = __builtin_bit_cast(float, (unsigned)hu << 16);
  bfpair r;
  r.hi = (short)hu;
  r.lo = (short)f2bf_rne(x - hf);
  return r;
}

// DPP-shuffled add: v + dpp(v). CTRL: 0xB1=quad xor1, 0x4E=quad xor2,
// 0x124=row_ror:4, 0x128=row_ror:8. Pure VALU latency, no LDS.
template <int CTRL>
__device__ __forceinline__ float dpp_add(float v) {
  int t = __builtin_amdgcn_update_dpp(0, __builtin_bit_cast(int, v), CTRL, 0xF,
                                      0xF, true);
  return v + __builtin_bit_cast(float, t);
}

// ---------------- Phase 1: scaled vectors u --------------------------------
__global__ void hh_scale(const float* __restrict__ vecs, float* __restrict__ u) {
  const int n = blockIdx.x;   // 0..271
  const int l = threadIdx.x;  // 0..63
  float4* uo = (float4*)(u + (long)n * 256) + l;
  if (n >= 258) {
    *uo = make_float4(0.f, 0.f, 0.f, 0.f);
    return;
  }
  const float4 v = *((const float4*)(vecs + (long)n * 256) + l);
  float p = v.x * v.x + v.y * v.y + v.z * v.z + v.w * v.w;
#pragma unroll
  for (int off = 32; off; off >>= 1) p += __shfl_xor(p, off);
  const float s = sqrtf(2.0f / (p + 1e-16f));
  *uo = make_float4(v.x * s, v.y * s, v.z * s, v.w * s);
}

// ---------------- Phase 2: chunked Q rows ----------------------------------
// 512 blocks x 64 threads. Block = (chunk c = bx>>6, rowgroup bx&63).
// Each block computes 4 rows of Q_c = H_{33c}..H_{33c+32} (33 steps);
// per-step dot-reduce stays in a 16-lane DPP row. Writes Qc and Qc^T.
__launch_bounds__(64, 1)
__global__ void hh_qchunk(const float* __restrict__ u,
                          float* __restrict__ Qc,
                          float* __restrict__ QcT) {
  const int l = threadIdx.x;
  const int chunk = blockIdx.x >> 6;   // 0..7
  const int rg = blockIdx.x & 63;      // 0..63
  const int r = l >> 4;
  const int c = l & 15;
  const int row = rg * 4 + r;
  const int col0 = c * 16;

  float q[16];
#pragma unroll
  for (int i = 0; i < 16; ++i) q[i] = (col0 + i == row) ? 1.f : 0.f;

  const float* ub = u + (long)chunk * 33 * 256 + col0;

  auto load16 = [&](float(&d)[16], int n) {
    const float4* v = (const float4*)(ub + (long)n * 256);
#pragma unroll
    for (int i = 0; i < 4; ++i) {
      float4 t = v[i];
      d[4 * i] = t.x; d[4 * i + 1] = t.y; d[4 * i + 2] = t.z; d[4 * i + 3] = t.w;
    }
  };

  auto step = [&](const float(&a)[16]) {
    float p0 = 0.f, p1 = 0.f, p2 = 0.f, p3 = 0.f;
#pragma unroll
    for (int e = 0; e < 4; ++e) {
      p0 = fmaf(q[e], a[e], p0);
      p1 = fmaf(q[4 + e], a[4 + e], p1);
      p2 = fmaf(q[8 + e], a[8 + e], p2);
      p3 = fmaf(q[12 + e], a[12 + e], p3);
    }
    float p = (p0 + p1) + (p2 + p3);
    p = dpp_add<0xB1>(p);
    p = dpp_add<0x4E>(p);
    p = dpp_add<0x124>(p);
    p = dpp_add<0x128>(p);
#pragma unroll
    for (int k = 0; k < 16; ++k) q[k] = fmaf(-p, a[k], q[k]);
  };

  float A0[16], A1[16];
  load16(A0, 0);
  load16(A1, 1);
  for (int n = 0; n < 32; n += 2) {
    step(A0);
    load16(A0, n + 2);
    step(A1);
    load16(A1, n + 3);  // row 33c+33 <= 264 < 272 pad, harmless
  }
  step(A0);  // step 32

  float4* out = (float4*)(Qc + (long)chunk * 65536 + row * 256 + col0);
#pragma unroll
  for (int i = 0; i < 4; ++i)
    out[i] = make_float4(q[4 * i], q[4 * i + 1], q[4 * i + 2], q[4 * i + 3]);
  // transposed copy: QcT[col][row] = q[col-col0]; stores don't stall the wave
  float* outT = QcT + (long)chunk * 65536 + row;
#pragma unroll
  for (int i = 0; i < 16; ++i) outT[(col0 + i) * 256] = q[i];
}

// ---------------- Phase 2b: split-MFMA merge (all-vector loads) ------------
// Product p: C_p = A_p * B_p, A_p = A0 + p*2*65536, B^T = BT0 + p*2*65536 +
// 65536 (pairs interleaved; outputs consecutive at C0/CT0 + p*65536).
// bf16 hi/lo split, 3-term MFMA (hi*hi + hi*lo + lo*hi), fp32 accumulate.
// Grid: nprod*64 blocks x 64 thr; one wave owns a 32x32 tile (2x2 frags).
// A read along k (row-major), B read along k via BT (row-major) -> all f32x4.
// to_bf16: final level writes bf16 Qb only.
__launch_bounds__(64)
__global__ void hh_merge(const float* __restrict__ A0,
                         const float* __restrict__ BT0,
                         float* __restrict__ C0, float* __restrict__ CT0,
                         unsigned short* __restrict__ outb, int to_bf16) {
  const int p = blockIdx.x >> 6;
  const int t = blockIdx.x & 63;
  const int ti = (t >> 3) * 32, tj = (t & 7) * 32;
  const int lane = threadIdx.x;
  const int fr = lane & 15, fg = lane >> 4;
  const float* A = A0 + (long)p * 2 * 65536;
  const float* BT = BT0 + (long)p * 2 * 65536 + 65536;

  f32x4 acc[2][2];
#pragma unroll
  for (int m = 0; m < 2; ++m)
#pragma unroll
    for (int n = 0; n < 2; ++n) acc[m][n] = (f32x4){0.f, 0.f, 0.f, 0.f};

  for (int kt = 0; kt < 8; ++kt) {
    const int k0 = kt * 32 + fg * 8;
    bf16x8 ahi[2], alo[2], bhi[2], blo[2];
#pragma unroll
    for (int m = 0; m < 2; ++m) {
      const float* ap = A + (long)(ti + m * 16 + fr) * 256 + k0;
      f32x4 x0 = *(const f32x4*)ap;
      f32x4 x1 = *(const f32x4*)(ap + 4);
#pragma unroll
      for (int e = 0; e < 4; ++e) {
        bfpair p0 = bf_split(x0[e]);
        bfpair p1 = bf_split(x1[e]);
        ahi[m][e] = p0.hi; alo[m][e] = p0.lo;
        ahi[m][4 + e] = p1.hi; alo[m][4 + e] = p1.lo;
      }
    }
#pragma unroll
    for (int n = 0; n < 2; ++n) {
      const float* bp = BT + (long)(tj + n * 16 + fr) * 256 + k0;
      f32x4 x0 = *(const f32x4*)bp;
      f32x4 x1 = *(const f32x4*)(bp + 4);
#pragma unroll
      for (int e = 0; e < 4; ++e) {
        bfpair p0 = bf_split(x0[e]);
        bfpair p1 = bf_split(x1[e]);
        bhi[n][e] = p0.hi; blo[n][e] = p0.lo;
        bhi[n][4 + e] = p1.hi; blo[n][4 + e] = p1.lo;
      }
    }
#pragma unroll
    for (int m = 0; m < 2; ++m)
#pragma unroll
      for (int n = 0; n < 2; ++n) {
        acc[m][n] = __builtin_amdgcn_mfma_f32_16x16x32_bf16(ahi[m], bhi[n],
                                                            acc[m][n], 0, 0, 0);
        acc[m][n] = __builtin_amdgcn_mfma_f32_16x16x32_bf16(ahi[m], blo[n],
                                                            acc[m][n], 0, 0, 0);
        acc[m][n] = __builtin_amdgcn_mfma_f32_16x16x32_bf16(alo[m], bhi[n],
                                                            acc[m][n], 0, 0, 0);
      }
  }

  // C/D layout: col = lane&15, row = (lane>>4)*4 + reg
#pragma unroll
  for (int m = 0; m < 2; ++m)
#pragma unroll
    for (int n = 0; n < 2; ++n)
#pragma unroll
      for (int rr = 0; rr < 4; ++rr) {
        const int grow = ti + m * 16 + fg * 4 + rr;
        const int gcol = tj + n * 16 + fr;
        const float val = acc[m][n][rr];
        if (to_bf16) {
          outb[grow * 256 + gcol] = f2bf_rne(val);
        } else {
          C0[(long)p * 65536 + grow * 256 + gcol] = val;
          CT0[(long)p * 65536 + gcol * 256 + grow] = val;
        }
      }
}

// ---------------- Phase 3: GEMM --------------------------------------------
// C[M=65536][256] = A[M][K=256](f32, cvt->bf16) * B[N=256][K=256](bf16, BT)
// Block: BM=128, BN=256, BK=32, 512 thr (8 waves). Wave grid 2x4, 64x64/wave.
// LDS 64KB dbuf; XOR-swizzled staging via pre-swizzled GLOBAL source address.
__launch_bounds__(512)
__global__ void hh_gemm(const float* __restrict__ X,
                        const unsigned short* __restrict__ Qb,
                        float* __restrict__ Y) {
  __shared__ __align__(128) char lds[65536];
  const int tid = threadIdx.x;
  const int lane = tid & 63;
  const int wid = tid >> 6;
  const int wm = wid >> 2;  // 0..1
  const int wn = wid & 3;   // 0..3
  const int fr = lane & 15;
  const int fg = lane >> 4;
  const long bm0 = (long)blockIdx.x * 128;

  auto stage = [&](int buf, int kt) {
#pragma unroll
    for (int r2 = 0; r2 < 2; ++r2) {
      int slot = r2 * 512 + tid;
      int row = slot >> 3, seg = slot & 7;
      int ps = seg ^ (row & 7);
      GLOAD_LDS16(X + (bm0 + row) * 256 + kt * 32 + ps * 4,
                  lds + buf * 16384 + slot * 16);
    }
#pragma unroll
    for (int r2 = 0; r2 < 2; ++r2) {
      int slot = r2 * 512 + tid;
      int row = slot >> 2, seg = slot & 3;
      int ps = seg ^ (row & 3);
      GLOAD_LDS16(Qb + row * 256 + kt * 32 + ps * 8,
                  lds + 32768 + buf * 16384 + slot * 16);
    }
  };

  f32x4 acc[4][4];
#pragma unroll
  for (int m = 0; m < 4; ++m)
#pragma unroll
    for (int n = 0; n < 4; ++n) acc[m][n] = (f32x4){0.f, 0.f, 0.f, 0.f};

  stage(0, 0);
  __syncthreads();

  for (int kt = 0; kt < 8; ++kt) {
    const int cur = kt & 1;
    if (kt < 7) stage(cur ^ 1, kt + 1);

    bf16x8 aF[4], bF[4];
#pragma unroll
    for (int m = 0; m < 4; ++m) {
      int row = wm * 64 + m * 16 + fr;
      int s0 = (2 * fg) ^ (row & 7);
      int s1 = (2 * fg + 1) ^ (row & 7);
      const f32x4 x0 = *(const f32x4*)(lds + cur * 16384 + row * 128 + s0 * 16);
      const f32x4 x1 = *(const f32x4*)(lds + cur * 16384 + row * 128 + s1 * 16);
      bf16x8 t;
      t[0] = (short)f2bf_rne(x0[0]);
      t[1] = (short)f2bf_rne(x0[1]);
      t[2] = (short)f2bf_rne(x0[2]);
      t[3] = (short)f2bf_rne(x0[3]);
      t[4] = (short)f2bf_rne(x1[0]);
      t[5] = (short)f2bf_rne(x1[1]);
      t[6] = (short)f2bf_rne(x1[2]);
      t[7] = (short)f2bf_rne(x1[3]);
      aF[m] = t;
    }
#pragma unroll
    for (int n = 0; n < 4; ++n) {
      int row = wn * 64 + n * 16 + fr;
      int ps = fg ^ (row & 3);
      bF[n] = *(const bf16x8*)(lds + 32768 + cur * 16384 + row * 64 + ps * 16);
    }
#pragma unroll
    for (int m = 0; m < 4; ++m)
#pragma unroll
      for (int n = 0; n < 4; ++n)
        acc[m][n] =
            __builtin_amdgcn_mfma_f32_16x16x32_bf16(aF[m], bF[n], acc[m][n], 0, 0, 0);
    __syncthreads();
  }

#pragma unroll
  for (int m = 0; m < 4; ++m)
#pragma unroll
    for (int n = 0; n < 4; ++n)
#pragma unroll
      for (int r = 0; r < 4; ++r) {
        long grow = bm0 + wm * 64 + m * 16 + fg * 4 + r;
        int gcol = wn * 64 + n * 16 + fr;
        Y[grow * 256 + gcol] = acc[m][n][r];
      }
}

// ---------------------------------------------------------------------------
extern "C" void kernel_launch(void* const* d_in, const int* in_sizes, int n_in,
                              void* d_out, int out_size, void* d_ws, size_t ws_size,
                              hipStream_t stream) {
  const float* x = (const float*)d_in[0];      // [65536][256] f32
  const float* vecs = (const float*)d_in[1];   // [258][256] f32
  float* y = (float*)d_out;                    // [65536][256] f32

  // d_ws: small buffers only (R5-proven footprint)
  char* ws = (char*)d_ws;
  float* u = (float*)ws;                                // 272x256 f32 (278528 B)
  unsigned short* Qb = (unsigned short*)(ws + 278528);  // 256x256 bf16 (131072 B)

  // Large intermediates in d_out scratch (dead before hh_gemm overwrites all)
  char* ob = (char*)d_out;
  float* Qc  = (float*)(ob);                 // 8 x 64KB f32 (2 MB)
  float* QcT = (float*)(ob + 2097152);       // 8 x 64KB f32 (2 MB)
  float* P   = (float*)(ob + 4194304);       // 4 x 64KB f32 (1 MB)
  float* PT  = (float*)(ob + 5242880);       // 4 x 64KB f32 (1 MB)
  float* R   = (float*)(ob + 6291456);       // 2 x 64KB f32 (512 KB)
  float* RT  = (float*)(ob + 6815744);       // 2 x 64KB f32 (512 KB)

  hh_scale<<<272, 64, 0, stream>>>(vecs, u);
  hh_qchunk<<<512, 64, 0, stream>>>(u, Qc, QcT);
  hh_merge<<<256, 64, 0, stream>>>(Qc, QcT, P, PT, nullptr, 0);  // 4 products
  hh_merge<<<128, 64, 0, stream>>>(P, PT, R, RT, nullptr, 0);    // 2 products
  hh_merge<<<64, 64, 0, stream>>>(R, RT, nullptr, nullptr, Qb, 1); // -> Qb
  hh_gemm<<<512, 512, 0, stream>>>(x, Qb, y);
}

// Round 12
// 70.963 us; speedup vs baseline: 1.0662x; 1.0037x over previous
//
#include <hip/hip_runtime.h>

// ---------------------------------------------------------------------------
// y = x @ Q^T where Q = H_0 H_1 ... H_{N-1}, H_n = I - 2 v_n v_n^T/(v_n.v_n+eps)
// S=256, N=258, B=65536.
// Phase 1: u_n = sqrt(2/(v_n.v_n+eps)) * v_n  (rows 258..271 zeroed: no-op pad)
// Phase 2: 8 parallel chunk cascades Q_c = H_{33c}..H_{33c+32}; writes Qc AND
//          Qc^T (transposed copy costs only scatter STORES, which don't stall;
//          it buys fully VECTOR loads in the merge tree).
// Phase 2b: merge tree P=Qc*Qc, R=P*P, Q=R*R via bf16 hi/lo split MFMA.
//          All operand loads are f32x4 along k (A row-major, B via B^T).
//          R10's 13us/level was latency-bound scalar column loads + tiny
//          grids; this round: vector loads + 64-thr blocks (4x more blocks).
// Phase 3: GEMM y[b][j] = sum_k x[b][k] Qb[j][k]  (BT layout, bf16 MFMA)
//
// Scratch: d_ws holds u (272KB) + Qb (128KB). Qc/QcT/P/PT/R/RT (7MB) live in
// d_out (64MB), written before read every call, overwritten by hh_gemm.
// ---------------------------------------------------------------------------

#define GLOAD_LDS16(g, l)                                                      \
  __builtin_amdgcn_global_load_lds(                                            \
      (const __attribute__((address_space(1))) void*)(g),                      \
      (__attribute__((address_space(3))) void*)(l), 16, 0, 0)

typedef __attribute__((ext_vector_type(8))) short bf16x8;
typedef __attribute__((ext_vector_type(4))) float f32x4;

__device__ __forceinline__ unsigned short f2bf_rne(float f) {
  unsigned u = __builtin_bit_cast(unsigned, f);
  return (unsigned short)((u + 0x7fffu + ((u >> 16) & 1u)) >> 16);
}

struct bfpair { short hi, lo; };

// split fp32 -> hi(bf16) + lo(bf16), x ~= hi + lo, |err| ~ 2^-16 |x|
__device__ __forceinline__ bfpair bf_split(float x) {
  unsigned short hu = f2bf_rne(x);
  float hf = __builtin_bit_cast(float, (unsigned)hu << 16);
  bfpair r;
  r.hi = (short)hu;
  r.lo = (short)f2bf_rne(x - hf);
  return r;
}

// DPP-shuffled add: v + dpp(v). CTRL: 0xB1=quad xor1, 0x4E=quad xor2,
// 0x124=row_ror:4, 0x128=row_ror:8. Pure VALU latency, no LDS.
template <int CTRL>
__device__ __forceinline__ float dpp_add(float v) {
  int t = __builtin_amdgcn_update_dpp(0, __builtin_bit_cast(int, v), CTRL, 0xF,
                                      0xF, true);
  return v + __builtin_bit_cast(float, t);
}

// ---------------- Phase 1: scaled vectors u --------------------------------
__global__ void hh_scale(const float* __restrict__ vecs, float* __restrict__ u) {
  const int n = blockIdx.x;   // 0..271
  const int l = threadIdx.x;  // 0..63
  float4* uo = (float4*)(u + (long)n * 256) + l;
  if (n >= 258) {
    *uo = make_float4(0.f, 0.f, 0.f, 0.f);
    return;
  }
  const float4 v = *((const float4*)(vecs + (long)n * 256) + l);
  float p = v.x * v.x + v.y * v.y + v.z * v.z + v.w * v.w;
#pragma unroll
  for (int off = 32; off; off >>= 1) p += __shfl_xor(p, off);
  const float s = sqrtf(2.0f / (p + 1e-16f));
  *uo = make_float4(v.x * s, v.y * s, v.z * s, v.w * s);
}

// ---------------- Phase 2: chunked Q rows ----------------------------------
// 512 blocks x 64 threads. Block = (chunk c = bx>>6, rowgroup bx&63).
// Each block computes 4 rows of Q_c = H_{33c}..H_{33c+32} (33 steps);
// per-step dot-reduce stays in a 16-lane DPP row. Writes Qc and Qc^T.
__launch_bounds__(64, 1)
__global__ void hh_qchunk(const float* __restrict__ u,
                          float* __restrict__ Qc,
                          float* __restrict__ QcT) {
  const int l = threadIdx.x;
  const int chunk = blockIdx.x >> 6;   // 0..7
  const int rg = blockIdx.x & 63;      // 0..63
  const int r = l >> 4;
  const int c = l & 15;
  const int row = rg * 4 + r;
  const int col0 = c * 16;

  float q[16];
#pragma unroll
  for (int i = 0; i < 16; ++i) q[i] = (col0 + i == row) ? 1.f : 0.f;

  const float* ub = u + (long)chunk * 33 * 256 + col0;

  auto load16 = [&](float(&d)[16], int n) {
    const float4* v = (const float4*)(ub + (long)n * 256);
#pragma unroll
    for (int i = 0; i < 4; ++i) {
      float4 t = v[i];
      d[4 * i] = t.x; d[4 * i + 1] = t.y; d[4 * i + 2] = t.z; d[4 * i + 3] = t.w;
    }
  };

  auto step = [&](const float(&a)[16]) {
    float p0 = 0.f, p1 = 0.f, p2 = 0.f, p3 = 0.f;
#pragma unroll
    for (int e = 0; e < 4; ++e) {
      p0 = fmaf(q[e], a[e], p0);
      p1 = fmaf(q[4 + e], a[4 + e], p1);
      p2 = fmaf(q[8 + e], a[8 + e], p2);
      p3 = fmaf(q[12 + e], a[12 + e], p3);
    }
    float p = (p0 + p1) + (p2 + p3);
    p = dpp_add<0xB1>(p);
    p = dpp_add<0x4E>(p);
    p = dpp_add<0x124>(p);
    p = dpp_add<0x128>(p);
#pragma unroll
    for (int k = 0; k < 16; ++k) q[k] = fmaf(-p, a[k], q[k]);
  };

  float A0[16], A1[16];
  load16(A0, 0);
  load16(A1, 1);
  for (int n = 0; n < 32; n += 2) {
    step(A0);
    load16(A0, n + 2);
    step(A1);
    load16(A1, n + 3);  // row 33c+33 <= 264 < 272 pad, harmless
  }
  step(A0);  // step 32

  float4* out = (float4*)(Qc + (long)chunk * 65536 + row * 256 + col0);
#pragma unroll
  for (int i = 0; i < 4; ++i)
    out[i] = make_float4(q[4 * i], q[4 * i + 1], q[4 * i + 2], q[4 * i + 3]);
  // transposed copy: QcT[col][row] = q[col-col0]; stores don't stall the wave
  float* outT = QcT + (long)chunk * 65536 + row;
#pragma unroll
  for (int i = 0; i < 16; ++i) outT[(col0 + i) * 256] = q[i];
}

// ---------------- Phase 2b: split-MFMA merge (all-vector loads) ------------
// Product p: C_p = A_p * B_p, A_p = A0 + p*2*65536, B^T = BT0 + p*2*65536 +
// 65536 (pairs interleaved; outputs consecutive at C0/CT0 + p*65536).
// bf16 hi/lo split, 3-term MFMA (hi*hi + hi*lo + lo*hi), fp32 accumulate.
// Grid: nprod*64 blocks x 64 thr; one wave owns a 32x32 tile (2x2 frags).
// A read along k (row-major), B read along k via BT (row-major) -> all f32x4.
// to_bf16: final level writes bf16 Qb only.
__launch_bounds__(64)
__global__ void hh_merge(const float* __restrict__ A0,
                         const float* __restrict__ BT0,
                         float* __restrict__ C0, float* __restrict__ CT0,
                         unsigned short* __restrict__ outb, int to_bf16) {
  const int p = blockIdx.x >> 6;
  const int t = blockIdx.x & 63;
  const int ti = (t >> 3) * 32, tj = (t & 7) * 32;
  const int lane = threadIdx.x;
  const int fr = lane & 15, fg = lane >> 4;
  const float* A = A0 + (long)p * 2 * 65536;
  const float* BT = BT0 + (long)p * 2 * 65536 + 65536;

  f32x4 acc[2][2];
#pragma unroll
  for (int m = 0; m < 2; ++m)
#pragma unroll
    for (int n = 0; n < 2; ++n) acc[m][n] = (f32x4){0.f, 0.f, 0.f, 0.f};

  for (int kt = 0; kt < 8; ++kt) {
    const int k0 = kt * 32 + fg * 8;
    bf16x8 ahi[2], alo[2], bhi[2], blo[2];
#pragma unroll
    for (int m = 0; m < 2; ++m) {
      const float* ap = A + (long)(ti + m * 16 + fr) * 256 + k0;
      f32x4 x0 = *(const f32x4*)ap;
      f32x4 x1 = *(const f32x4*)(ap + 4);
#pragma unroll
      for (int e = 0; e < 4; ++e) {
        bfpair p0 = bf_split(x0[e]);
        bfpair p1 = bf_split(x1[e]);
        ahi[m][e] = p0.hi; alo[m][e] = p0.lo;
        ahi[m][4 + e] = p1.hi; alo[m][4 + e] = p1.lo;
      }
    }
#pragma unroll
    for (int n = 0; n < 2; ++n) {
      const float* bp = BT + (long)(tj + n * 16 + fr) * 256 + k0;
      f32x4 x0 = *(const f32x4*)bp;
      f32x4 x1 = *(const f32x4*)(bp + 4);
#pragma unroll
      for (int e = 0; e < 4; ++e) {
        bfpair p0 = bf_split(x0[e]);
        bfpair p1 = bf_split(x1[e]);
        bhi[n][e] = p0.hi; blo[n][e] = p0.lo;
        bhi[n][4 + e] = p1.hi; blo[n][4 + e] = p1.lo;
      }
    }
#pragma unroll
    for (int m = 0; m < 2; ++m)
#pragma unroll
      for (int n = 0; n < 2; ++n) {
        acc[m][n] = __builtin_amdgcn_mfma_f32_16x16x32_bf16(ahi[m], bhi[n],
                                                            acc[m][n], 0, 0, 0);
        acc[m][n] = __builtin_amdgcn_mfma_f32_16x16x32_bf16(ahi[m], blo[n],
                                                            acc[m][n], 0, 0, 0);
        acc[m][n] = __builtin_amdgcn_mfma_f32_16x16x32_bf16(alo[m], bhi[n],
                                                            acc[m][n], 0, 0, 0);
      }
  }

  // C/D layout: col = lane&15, row = (lane>>4)*4 + reg
#pragma unroll
  for (int m = 0; m < 2; ++m)
#pragma unroll
    for (int n = 0; n < 2; ++n)
#pragma unroll
      for (int rr = 0; rr < 4; ++rr) {
        const int grow = ti + m * 16 + fg * 4 + rr;
        const int gcol = tj + n * 16 + fr;
        const float val = acc[m][n][rr];
        if (to_bf16) {
          outb[grow * 256 + gcol] = f2bf_rne(val);
        } else {
          C0[(long)p * 65536 + grow * 256 + gcol] = val;
          CT0[(long)p * 65536 + gcol * 256 + grow] = val;
        }
      }
}

// ---------------- Phase 3: GEMM --------------------------------------------
// C[M=65536][256] = A[M][K=256](f32, cvt->bf16) * B[N=256][K=256](bf16, BT)
// Block: BM=128, BN=256, BK=32, 512 thr (8 waves). Wave grid 2x4, 64x64/wave.
// LDS 64KB dbuf; XOR-swizzled staging via pre-swizzled GLOBAL source address.
__launch_bounds__(512)
__global__ void hh_gemm(const float* __restrict__ X,
                        const unsigned short* __restrict__ Qb,
                        float* __restrict__ Y) {
  __shared__ __align__(128) char lds[65536];
  const int tid = threadIdx.x;
  const int lane = tid & 63;
  const int wid = tid >> 6;
  const int wm = wid >> 2;  // 0..1
  const int wn = wid & 3;   // 0..3
  const int fr = lane & 15;
  const int fg = lane >> 4;
  const long bm0 = (long)blockIdx.x * 128;

  auto stage = [&](int buf, int kt) {
#pragma unroll
    for (int r2 = 0; r2 < 2; ++r2) {
      int slot = r2 * 512 + tid;
      int row = slot >> 3, seg = slot & 7;
      int ps = seg ^ (row & 7);
      GLOAD_LDS16(X + (bm0 + row) * 256 + kt * 32 + ps * 4,
                  lds + buf * 16384 + slot * 16);
    }
#pragma unroll
    for (int r2 = 0; r2 < 2; ++r2) {
      int slot = r2 * 512 + tid;
      int row = slot >> 2, seg = slot & 3;
      int ps = seg ^ (row & 3);
      GLOAD_LDS16(Qb + row * 256 + kt * 32 + ps * 8,
                  lds + 32768 + buf * 16384 + slot * 16);
    }
  };

  f32x4 acc[4][4];
#pragma unroll
  for (int m = 0; m < 4; ++m)
#pragma unroll
    for (int n = 0; n < 4; ++n) acc[m][n] = (f32x4){0.f, 0.f, 0.f, 0.f};

  stage(0, 0);
  __syncthreads();

  for (int kt = 0; kt < 8; ++kt) {
    const int cur = kt & 1;
    if (kt < 7) stage(cur ^ 1, kt + 1);

    bf16x8 aF[4], bF[4];
#pragma unroll
    for (int m = 0; m < 4; ++m) {
      int row = wm * 64 + m * 16 + fr;
      int s0 = (2 * fg) ^ (row & 7);
      int s1 = (2 * fg + 1) ^ (row & 7);
      const f32x4 x0 = *(const f32x4*)(lds + cur * 16384 + row * 128 + s0 * 16);
      const f32x4 x1 = *(const f32x4*)(lds + cur * 16384 + row * 128 + s1 * 16);
      bf16x8 t;
      t[0] = (short)f2bf_rne(x0[0]);
      t[1] = (short)f2bf_rne(x0[1]);
      t[2] = (short)f2bf_rne(x0[2]);
      t[3] = (short)f2bf_rne(x0[3]);
      t[4] = (short)f2bf_rne(x1[0]);
      t[5] = (short)f2bf_rne(x1[1]);
      t[6] = (short)f2bf_rne(x1[2]);
      t[7] = (short)f2bf_rne(x1[3]);
      aF[m] = t;
    }
#pragma unroll
    for (int n = 0; n < 4; ++n) {
      int row = wn * 64 + n * 16 + fr;
      int ps = fg ^ (row & 3);
      bF[n] = *(const bf16x8*)(lds + 32768 + cur * 16384 + row * 64 + ps * 16);
    }
#pragma unroll
    for (int m = 0; m < 4; ++m)
#pragma unroll
      for (int n = 0; n < 4; ++n)
        acc[m][n] =
            __builtin_amdgcn_mfma_f32_16x16x32_bf16(aF[m], bF[n], acc[m][n], 0, 0, 0);
    __syncthreads();
  }

#pragma unroll
  for (int m = 0; m < 4; ++m)
#pragma unroll
    for (int n = 0; n < 4; ++n)
#pragma unroll
      for (int r = 0; r < 4; ++r) {
        long grow = bm0 + wm * 64 + m * 16 + fg * 4 + r;
        int gcol = wn * 64 + n * 16 + fr;
        Y[grow * 256 + gcol] = acc[m][n][r];
      }
}

// ---------------------------------------------------------------------------
extern "C" void kernel_launch(void* const* d_in, const int* in_sizes, int n_in,
                              void* d_out, int out_size, void* d_ws, size_t ws_size,
                              hipStream_t stream) {
  const float* x = (const float*)d_in[0];      // [65536][256] f32
  const float* vecs = (const float*)d_in[1];   // [258][256] f32
  float* y = (float*)d_out;                    // [65536][256] f32

  // d_ws: small buffers only (R5-proven footprint)
  char* ws = (char*)d_ws;
  float* u = (float*)ws;                                // 272x256 f32 (278528 B)
  unsigned short* Qb = (unsigned short*)(ws + 278528);  // 256x256 bf16 (131072 B)

  // Large intermediates in d_out scratch (dead before hh_gemm overwrites all)
  char* ob = (char*)d_out;
  float* Qc  = (float*)(ob);                 // 8 x 64KB f32 (2 MB)
  float* QcT = (float*)(ob + 2097152);       // 8 x 64KB f32 (2 MB)
  float* P   = (float*)(ob + 4194304);       // 4 x 64KB f32 (1 MB)
  float* PT  = (float*)(ob + 5242880);       // 4 x 64KB f32 (1 MB)
  float* R   = (float*)(ob + 6291456);       // 2 x 64KB f32 (512 KB)
  float* RT  = (float*)(ob + 6815744);       // 2 x 64KB f32 (512 KB)

  hh_scale<<<272, 64, 0, stream>>>(vecs, u);
  hh_qchunk<<<512, 64, 0, stream>>>(u, Qc, QcT);
  hh_merge<<<256, 64, 0, stream>>>(Qc, QcT, P, PT, nullptr, 0);  // 4 products
  hh_merge<<<128, 64, 0, stream>>>(P, PT, R, RT, nullptr, 0);    // 2 products
  hh_merge<<<64, 64, 0, stream>>>(R, RT, nullptr, nullptr, Qb, 1); // -> Qb
  hh_gemm<<<512, 512, 0, stream>>>(x, Qb, y);
}

// Round 13
// 62.775 us; speedup vs baseline: 1.2052x; 1.1304x over previous
//
#include <hip/hip_runtime.h>

// ---------------------------------------------------------------------------
// y = x @ Q^T where Q = H_0 H_1 ... H_{N-1}, H_n = I - 2 v_n v_n^T/(v_n.v_n+eps)
// S=256, N=258, B=65536.
// Phase 1 (fused into phase 2): c_n = 2/(v_n.v_n+eps) computed per-block.
// Phase 2: 8 parallel chunk cascades Q_c = H_{33c}..H_{33c+32} (33-step chains,
//          512 blocks; 16-lane DPP dot-reduce; c=0 pads are exact no-ops).
// Phase 2b: merge tree P=QcQc, R=PP, Q=RR (R8's LDS fp32 mm -- empirically the
//          fastest merge form measured; levels are launch/latency-bound).
// Phase 3: GEMM y[b][j] = sum_k x[b][k] Qb[j][k]  (BT layout, bf16 MFMA)
//
// Calibrated model (R1..R12): ~3us/kernel overhead, gemm ~24, qchunk ~6.5,
// merge ~5/level. This round: -1 kernel (scale fused) and revert to best mm.
// Scratch: d_ws holds Qb (128KB). Qc/P/R (3.5MB) live in d_out (64MB),
// written before read every call, fully overwritten by hh_gemm afterwards.
// ---------------------------------------------------------------------------

#define GLOAD_LDS16(g, l)                                                      \
  __builtin_amdgcn_global_load_lds(                                            \
      (const __attribute__((address_space(1))) void*)(g),                      \
      (__attribute__((address_space(3))) void*)(l), 16, 0, 0)

typedef __attribute__((ext_vector_type(8))) short bf16x8;
typedef __attribute__((ext_vector_type(4))) float f32x4;

__device__ __forceinline__ unsigned short f2bf_rne(float f) {
  unsigned u = __builtin_bit_cast(unsigned, f);
  return (unsigned short)((u + 0x7fffu + ((u >> 16) & 1u)) >> 16);
}

// DPP-shuffled add: v + dpp(v). CTRL: 0xB1=quad xor1, 0x4E=quad xor2,
// 0x124=row_ror:4, 0x128=row_ror:8. Pure VALU latency, no LDS.
template <int CTRL>
__device__ __forceinline__ float dpp_add(float v) {
  int t = __builtin_amdgcn_update_dpp(0, __builtin_bit_cast(int, v), CTRL, 0xF,
                                      0xF, true);
  return v + __builtin_bit_cast(float, t);
}

// full 16-lane-group sum (all lanes get the sum)
__device__ __forceinline__ float dpp_sum16(float p) {
  p = dpp_add<0xB1>(p);   // quad xor1
  p = dpp_add<0x4E>(p);   // quad xor2
  p = dpp_add<0x124>(p);  // row_ror:4
  p = dpp_add<0x128>(p);  // row_ror:8
  return p;
}

// ---------------- Phase 2: chunked Q rows, norms fused ---------------------
// 512 blocks x 64 threads (1 wave). Block = (chunk=bx>>6, rowgroup=bx&63).
// Lane l: row-in-group r=l>>4, col-group c16=l&15 (16 contiguous cols).
// Prologue: the block's 16-lane groups compute c_n = 2/(v_n.v_n+eps) for the
// chunk's 33 rows (+3 pad zeros) into LDS. Chain: 33 steps of
// q -= c_n (q.v_n) v_n with 2-deep register prefetch of v rows.
__launch_bounds__(64, 1)
__global__ void hh_qchunk(const float* __restrict__ vecs,
                          float* __restrict__ Qc) {
  const int l = threadIdx.x;
  const int chunk = blockIdx.x >> 6;   // 0..7
  const int rg = blockIdx.x & 63;      // 0..63
  const int r = l >> 4;                // lane group 0..3
  const int cl = l & 15;               // lane in group
  const int row = rg * 4 + r;
  const int col0 = cl * 16;
  const int brow = chunk * 33;         // chunk's first global row

  __shared__ float cs[36];

  // ---- prologue: c_n for n = 0..35 (n>=33 or global row >=258 -> 0) ----
  for (int n = r; n < 36; n += 4) {
    const int gr = brow + n;
    const int grc = gr > 257 ? 257 : gr;
    const float4* vp = (const float4*)(vecs + (long)grc * 256 + col0);
    float s = 0.f;
#pragma unroll
    for (int i = 0; i < 4; ++i) {
      float4 t = vp[i];
      s += t.x * t.x + t.y * t.y + t.z * t.z + t.w * t.w;
    }
    s = dpp_sum16(s);
    if (cl == 0)
      cs[n] = (n < 33 && gr < 258) ? 2.0f / (s + 1e-16f) : 0.f;
  }
  __syncthreads();  // single wave; cheap ordering fence for LDS

  float q[16];
#pragma unroll
  for (int i = 0; i < 16; ++i) q[i] = (col0 + i == row) ? 1.f : 0.f;

  auto load16 = [&](float(&d)[16], int n) {
    const int gr = brow + n;
    const int grc = gr > 257 ? 257 : gr;  // clamped re-read; c=0 pad -> no-op
    const float4* v = (const float4*)(vecs + (long)grc * 256 + col0);
#pragma unroll
    for (int i = 0; i < 4; ++i) {
      float4 t = v[i];
      d[4 * i] = t.x; d[4 * i + 1] = t.y; d[4 * i + 2] = t.z; d[4 * i + 3] = t.w;
    }
  };

  auto step = [&](const float(&a)[16], float cc) {
    float p0 = 0.f, p1 = 0.f, p2 = 0.f, p3 = 0.f;
#pragma unroll
    for (int e = 0; e < 4; ++e) {
      p0 = fmaf(q[e], a[e], p0);
      p1 = fmaf(q[4 + e], a[4 + e], p1);
      p2 = fmaf(q[8 + e], a[8 + e], p2);
      p3 = fmaf(q[12 + e], a[12 + e], p3);
    }
    float p = dpp_sum16((p0 + p1) + (p2 + p3));
    const float s = cc * p;
#pragma unroll
    for (int k = 0; k < 16; ++k) q[k] = fmaf(-s, a[k], q[k]);
  };

  float A0[16], A1[16];
  load16(A0, 0);
  load16(A1, 1);
  float c0 = cs[0], c1 = cs[1];
  for (int n = 0; n < 32; n += 2) {
    const float cn0 = cs[n + 2], cn1 = cs[n + 3];  // prefetch c
    step(A0, c0);
    load16(A0, n + 2);
    step(A1, c1);
    load16(A1, n + 3);
    c0 = cn0; c1 = cn1;
  }
  step(A0, c0);  // step 32

  float4* out = (float4*)(Qc + (long)chunk * 65536 + row * 256 + col0);
#pragma unroll
  for (int i = 0; i < 4; ++i)
    out[i] = make_float4(q[4 * i], q[4 * i + 1], q[4 * i + 2], q[4 * i + 3]);
}

// ---------------- Phase 2b: fp32 merge GEMM (R8-proven form) ---------------
// C_b = A_b * B_b for consecutive 256x256 fp32 pairs in `in`
// (A=in+b*2*65536, B=A+65536). Grid = batch*64 blocks, 256 thr.
// Block computes a 32x32 tile; thread 2x2; K staged via LDS in 64-wide tiles.
// to_bf16: last level writes bf16 Qb instead of fp32.
__launch_bounds__(256)
__global__ void hh_mm(const float* __restrict__ in, float* __restrict__ out,
                      unsigned short* __restrict__ outb, int to_bf16) {
  const int b = blockIdx.x >> 6;
  const int t = blockIdx.x & 63;
  const int ti = (t >> 3) * 32, tj = (t & 7) * 32;
  const int tid = threadIdx.x;
  const int tx = tid & 15, ty = tid >> 4;
  const float* A = in + (long)b * 2 * 65536;
  const float* Bm = A + 65536;

  __shared__ float As[32][68];  // pad 68: row-stride bank-offset for col reads
  __shared__ float Bs[64][36];  // pad 36 keeps float4 alignment

  float acc00 = 0.f, acc01 = 0.f, acc10 = 0.f, acc11 = 0.f;

  for (int k0 = 0; k0 < 256; k0 += 64) {
#pragma unroll
    for (int u0 = 0; u0 < 2048; u0 += 1024) {
      int idx = u0 + tid * 4;
      int rr = idx >> 6, cc = idx & 63;
      *(float4*)&As[rr][cc] = *(const float4*)&A[(ti + rr) * 256 + k0 + cc];
      int kk = idx >> 5, jj = idx & 31;
      *(float4*)&Bs[kk][jj] = *(const float4*)&Bm[(k0 + kk) * 256 + tj + jj];
    }
    __syncthreads();
#pragma unroll 8
    for (int kk = 0; kk < 64; ++kk) {
      float a0 = As[2 * ty][kk], a1 = As[2 * ty + 1][kk];
      float b0 = Bs[kk][2 * tx], b1 = Bs[kk][2 * tx + 1];
      acc00 = fmaf(a0, b0, acc00);
      acc01 = fmaf(a0, b1, acc01);
      acc10 = fmaf(a1, b0, acc10);
      acc11 = fmaf(a1, b1, acc11);
    }
    __syncthreads();
  }

  const int gi = ti + 2 * ty, gj = tj + 2 * tx;
  if (to_bf16) {
    unsigned short* o = outb + (long)b * 65536;
    o[gi * 256 + gj] = f2bf_rne(acc00);
    o[gi * 256 + gj + 1] = f2bf_rne(acc01);
    o[(gi + 1) * 256 + gj] = f2bf_rne(acc10);
    o[(gi + 1) * 256 + gj + 1] = f2bf_rne(acc11);
  } else {
    float* o = out + (long)b * 65536;
    o[gi * 256 + gj] = acc00;
    o[gi * 256 + gj + 1] = acc01;
    o[(gi + 1) * 256 + gj] = acc10;
    o[(gi + 1) * 256 + gj + 1] = acc11;
  }
}

// ---------------- Phase 3: GEMM --------------------------------------------
// C[M=65536][256] = A[M][K=256](f32, cvt->bf16) * B[N=256][K=256](bf16, BT)
// Block: BM=128, BN=256, BK=32, 512 thr (8 waves). Wave grid 2x4, 64x64/wave.
// LDS 64KB dbuf; XOR-swizzled staging via pre-swizzled GLOBAL source address.
__launch_bounds__(512)
__global__ void hh_gemm(const float* __restrict__ X,
                        const unsigned short* __restrict__ Qb,
                        float* __restrict__ Y) {
  __shared__ __align__(128) char lds[65536];
  const int tid = threadIdx.x;
  const int lane = tid & 63;
  const int wid = tid >> 6;
  const int wm = wid >> 2;  // 0..1
  const int wn = wid & 3;   // 0..3
  const int fr = lane & 15;
  const int fg = lane >> 4;
  const long bm0 = (long)blockIdx.x * 128;

  auto stage = [&](int buf, int kt) {
#pragma unroll
    for (int r2 = 0; r2 < 2; ++r2) {
      int slot = r2 * 512 + tid;
      int row = slot >> 3, seg = slot & 7;
      int ps = seg ^ (row & 7);
      GLOAD_LDS16(X + (bm0 + row) * 256 + kt * 32 + ps * 4,
                  lds + buf * 16384 + slot * 16);
    }
#pragma unroll
    for (int r2 = 0; r2 < 2; ++r2) {
      int slot = r2 * 512 + tid;
      int row = slot >> 2, seg = slot & 3;
      int ps = seg ^ (row & 3);
      GLOAD_LDS16(Qb + row * 256 + kt * 32 + ps * 8,
                  lds + 32768 + buf * 16384 + slot * 16);
    }
  };

  f32x4 acc[4][4];
#pragma unroll
  for (int m = 0; m < 4; ++m)
#pragma unroll
    for (int n = 0; n < 4; ++n) acc[m][n] = (f32x4){0.f, 0.f, 0.f, 0.f};

  stage(0, 0);
  __syncthreads();

  for (int kt = 0; kt < 8; ++kt) {
    const int cur = kt & 1;
    if (kt < 7) stage(cur ^ 1, kt + 1);

    bf16x8 aF[4], bF[4];
#pragma unroll
    for (int m = 0; m < 4; ++m) {
      int row = wm * 64 + m * 16 + fr;
      int s0 = (2 * fg) ^ (row & 7);
      int s1 = (2 * fg + 1) ^ (row & 7);
      const f32x4 x0 = *(const f32x4*)(lds + cur * 16384 + row * 128 + s0 * 16);
      const f32x4 x1 = *(const f32x4*)(lds + cur * 16384 + row * 128 + s1 * 16);
      bf16x8 t;
      t[0] = (short)f2bf_rne(x0[0]);
      t[1] = (short)f2bf_rne(x0[1]);
      t[2] = (short)f2bf_rne(x0[2]);
      t[3] = (short)f2bf_rne(x0[3]);
      t[4] = (short)f2bf_rne(x1[0]);
      t[5] = (short)f2bf_rne(x1[1]);
      t[6] = (short)f2bf_rne(x1[2]);
      t[7] = (short)f2bf_rne(x1[3]);
      aF[m] = t;
    }
#pragma unroll
    for (int n = 0; n < 4; ++n) {
      int row = wn * 64 + n * 16 + fr;
      int ps = fg ^ (row & 3);
      bF[n] = *(const bf16x8*)(lds + 32768 + cur * 16384 + row * 64 + ps * 16);
    }
#pragma unroll
    for (int m = 0; m < 4; ++m)
#pragma unroll
      for (int n = 0; n < 4; ++n)
        acc[m][n] =
            __builtin_amdgcn_mfma_f32_16x16x32_bf16(aF[m], bF[n], acc[m][n], 0, 0, 0);
    __syncthreads();
  }

#pragma unroll
  for (int m = 0; m < 4; ++m)
#pragma unroll
    for (int n = 0; n < 4; ++n)
#pragma unroll
      for (int r = 0; r < 4; ++r) {
        long grow = bm0 + wm * 64 + m * 16 + fg * 4 + r;
        int gcol = wn * 64 + n * 16 + fr;
        Y[grow * 256 + gcol] = acc[m][n][r];
      }
}

// ---------------------------------------------------------------------------
extern "C" void kernel_launch(void* const* d_in, const int* in_sizes, int n_in,
                              void* d_out, int out_size, void* d_ws, size_t ws_size,
                              hipStream_t stream) {
  const float* x = (const float*)d_in[0];      // [65536][256] f32
  const float* vecs = (const float*)d_in[1];   // [258][256] f32
  float* y = (float*)d_out;                    // [65536][256] f32

  // d_ws: only Qb (128KB; well under R5-proven 410KB budget)
  unsigned short* Qb = (unsigned short*)d_ws;

  // Large intermediates in d_out scratch (dead before hh_gemm overwrites all)
  char* ob = (char*)d_out;
  float* Qc = (float*)(ob);                 // 8 x 256x256 f32 (2 MB)
  float* P = (float*)(ob + 2097152);        // 4 x 256x256 f32 (1 MB)
  float* R = (float*)(ob + 3145728);        // 2 x 256x256 f32 (512 KB)

  hh_qchunk<<<512, 64, 0, stream>>>(vecs, Qc);
  hh_mm<<<256, 256, 0, stream>>>(Qc, P, nullptr, 0);   // 4 pair-products
  hh_mm<<<128, 256, 0, stream>>>(P, R, nullptr, 0);    // 2 pair-products
  hh_mm<<<64, 256, 0, stream>>>(R, nullptr, Qb, 1);    // final -> bf16 Qb
  hh_gemm<<<512, 512, 0, stream>>>(x, Qb, y);
}